// Round 5
// baseline (213.968 us; speedup 1.0000x reference)
//
#include <hip/hip_runtime.h>
#include <hip/hip_bf16.h>
#include <math.h>

// Problem constants (from reference)
#define MSEG  4096     // number of graphs / segments
#define NNODE 262144   // total nodes
#define DDIM  128      // d_h == d_x == 128
#define PROJ_ROWS 16   // h-rows per block in the proj GEMM
#define WPB   4        // waves (=segments) per block
#define PASS  8        // nodes per pass (8-lanes-per-row mapping)

// ---------------- cross-lane helpers ----------------
// DPP row_shr:N, invalid source -> 0 (sum identity)
template<int CTRL>
__device__ __forceinline__ float dpp_zero(float v) {
    return __int_as_float(__builtin_amdgcn_update_dpp(
        0, __float_as_int(v), CTRL, 0xF, 0xF, true));
}
// DPP row_shr:N, invalid source -> keep own (max identity)
template<int CTRL>
__device__ __forceinline__ float dpp_self(float v) {
    int iv = __float_as_int(v);
    return __int_as_float(__builtin_amdgcn_update_dpp(iv, iv, CTRL, 0xF, 0xF, false));
}
__device__ __forceinline__ float rdlane15(float v) {
    return __int_as_float(__builtin_amdgcn_readlane(__float_as_int(v), 15));
}
template<int PAT>
__device__ __forceinline__ float swz(float v) {
    return __int_as_float(__builtin_amdgcn_ds_swizzle(__float_as_int(v), PAT));
}
// sum over each 8-lane window [8k,8k+7]; lane 8k+7 holds the exact window sum
// (inclusive-scan property: lane 8k+7 only ever pulls from lanes >= 8k)
__device__ __forceinline__ float red8(float v) {
    v += dpp_zero<0x111>(v);   // row_shr:1
    v += dpp_zero<0x112>(v);   // row_shr:2
    v += dpp_zero<0x114>(v);   // row_shr:4
    return v;
}

// Kernel 1: segment start offsets (segment_ids is sorted).
__global__ __launch_bounds__(256) void seg_starts_kernel(
    const int* __restrict__ seg, int* __restrict__ starts)
{
    int i = blockIdx.x * blockDim.x + threadIdx.x;
    if (i >= NNODE) return;
    int s = seg[i];
    int prev = (i == 0) ? -1 : seg[i - 1];
    for (int g = prev + 1; g <= s; ++g) starts[g] = i;
    if (i == NNODE - 1)
        for (int g = s + 1; g <= MSEG; ++g) starts[g] = NNODE;
}

// Kernel 2: proj = h @ a (4096x128 @ 128x128), a staged once per block in LDS.
__global__ __launch_bounds__(256) void proj_kernel(
    const float* __restrict__ h, const float* __restrict__ a,
    float* __restrict__ proj)
{
    __shared__ __align__(16) float a_lds[DDIM * DDIM];        // 64 KB
    __shared__ __align__(16) float h_lds[PROJ_ROWS * DDIM];   // 8 KB
    const int tid = threadIdx.x;
    const int g0  = blockIdx.x * PROJ_ROWS;

    const float4* a4  = (const float4*)a;
    float4*       al4 = (float4*)a_lds;
    #pragma unroll
    for (int j = 0; j < (DDIM * DDIM / 4) / 256; ++j)
        al4[j * 256 + tid] = a4[j * 256 + tid];
    const float4* h4  = (const float4*)(h + (size_t)g0 * DDIM);
    float4*       hl4 = (float4*)h_lds;
    #pragma unroll
    for (int j = 0; j < (PROJ_ROWS * DDIM / 4) / 256; ++j)
        hl4[j * 256 + tid] = h4[j * 256 + tid];
    __syncthreads();

    const int dp = tid & 63;
    const int rh = tid >> 6;
    const float2* al2 = (const float2*)a_lds;
    #pragma unroll
    for (int rr = 0; rr < PROJ_ROWS / 4; ++rr) {
        const int r = rh * (PROJ_ROWS / 4) + rr;
        float2 p = make_float2(0.f, 0.f);
        #pragma unroll 8
        for (int k = 0; k < DDIM; ++k) {
            const float  hv = h_lds[r * DDIM + k];
            const float2 av = al2[k * 64 + dp];
            p.x += hv * av.x;
            p.y += hv * av.y;
        }
        ((float2*)(proj + (size_t)(g0 + r) * DDIM))[dp] = p;
    }
}

// Kernel 3: ONE WAVE PER SEGMENT — barrier-free streaming.
// lane: q = lane>>3 owns dims [16q,16q+16) (4 float4); r = lane&7 is the row
// within an 8-node pass. Score reduce across q: xor8+xor16 (ds_swizzle) +
// xor32 (shfl). Pass stats via DPP row-reductions (each 16-lane row holds every
// r twice -> sum * 0.5); all softmax state per-lane (wave-uniform). Next pass
// prefetched into a second register set. No __syncthreads, no LDS storage.
__global__ __launch_bounds__(256) void attn_seg_kernel(
    const float* __restrict__ x,
    const float* __restrict__ proj,
    const int*   __restrict__ starts,
    float*       __restrict__ out)
{
    const int tid  = threadIdx.x;
    const int lane = tid & 63;
    const int g    = blockIdx.x * WPB + (tid >> 6);   // wave-uniform
    const int q    = lane >> 3;                       // dim-16 group [0,8)
    const int r    = lane & 7;                        // row in pass [0,8)

    const int start = starts[g];
    const int end   = starts[g + 1];

    float4* out4 = (float4*)out + (size_t)g * 32 + q * 4;

    if (start >= end) {                               // empty segment -> zeros
        if (r == 7) {
            #pragma unroll
            for (int j = 0; j < 4; ++j) out4[j] = make_float4(0.f, 0.f, 0.f, 0.f);
        }
        return;
    }

    const float4* pp = (const float4*)proj + (size_t)g * 32 + q * 4;
    float4 pj[4];
    #pragma unroll
    for (int j = 0; j < 4; ++j) pj[j] = pp[j];

    const float4* __restrict__ xb = (const float4*)x;

    int cs  = start;
    int n_c = min(PASS, end - cs);
    float4 xc[4], xn[4];
    #pragma unroll
    for (int j = 0; j < 4; ++j) xc[j] = make_float4(0.f, 0.f, 0.f, 0.f);
    if (r < n_c) {
        const float4* p = xb + (size_t)(cs + r) * 32 + q * 4;
        #pragma unroll
        for (int j = 0; j < 4; ++j) xc[j] = p[j];
    }

    float m_run = -INFINITY;                          // wave-uniform
    float l_run = 0.f;                                // wave-uniform
    float4 acc[4];
    #pragma unroll
    for (int j = 0; j < 4; ++j) acc[j] = make_float4(0.f, 0.f, 0.f, 0.f);

    while (true) {
        // ---- 16-dim partial dot, then sum across the 8 q-groups (same r) --
        float ps = 0.f;
        #pragma unroll
        for (int j = 0; j < 4; ++j)
            ps += xc[j].x * pj[j].x + xc[j].y * pj[j].y
                + xc[j].z * pj[j].z + xc[j].w * pj[j].w;
        ps += swz<0x201F>(ps);                        // lane ^ 8
        ps += swz<0x401F>(ps);                        // lane ^ 16
        ps += __shfl_xor(ps, 32, 64);                 // lane ^ 32
        const float s = (r < n_c) ? ps : -INFINITY;   // mask invalid rows

        // ---- pass max over rows (replicated; readlane -> uniform) ---------
        float mv = s;
        mv = fmaxf(mv, dpp_self<0x111>(mv));
        mv = fmaxf(mv, dpp_self<0x112>(mv));
        mv = fmaxf(mv, dpp_self<0x114>(mv));
        mv = fmaxf(mv, dpp_self<0x118>(mv));
        const float m_new = fmaxf(m_run, rdlane15(mv));

        // ---- prefetch next pass (loads in flight through the stats) -------
        const int cs2 = cs + PASS;
        int n2 = 0;
        #pragma unroll
        for (int j = 0; j < 4; ++j) xn[j] = make_float4(0.f, 0.f, 0.f, 0.f);
        if (cs2 < end) {
            n2 = min(PASS, end - cs2);
            if (r < n2) {
                const float4* p = xb + (size_t)(cs2 + r) * 32 + q * 4;
                #pragma unroll
                for (int j = 0; j < 4; ++j) xn[j] = p[j];
            }
        }

        // ---- e, pass denom (each r appears twice per 16-row -> *0.5) ------
        const float e = __expf(s - m_new);            // s=-inf -> 0
        float ev = e;
        ev += dpp_zero<0x111>(ev);
        ev += dpp_zero<0x112>(ev);
        ev += dpp_zero<0x114>(ev);
        ev += dpp_zero<0x118>(ev);
        const float l_pass = 0.5f * rdlane15(ev);

        const float alpha = __expf(m_run - m_new);    // first pass: exp(-inf)=0
        l_run = l_run * alpha + l_pass;
        m_run = m_new;
        #pragma unroll
        for (int j = 0; j < 4; ++j) {
            acc[j].x = acc[j].x * alpha + e * xc[j].x;
            acc[j].y = acc[j].y * alpha + e * xc[j].y;
            acc[j].z = acc[j].z * alpha + e * xc[j].z;
            acc[j].w = acc[j].w * alpha + e * xc[j].w;
        }

        if (cs2 >= end) break;
        cs = cs2; n_c = n2;
        #pragma unroll
        for (int j = 0; j < 4; ++j) xc[j] = xn[j];
    }

    // ---- epilogue: sum acc over the 8 r-lanes of this q-group -------------
    #pragma unroll
    for (int j = 0; j < 4; ++j) {
        acc[j].x = red8(acc[j].x);
        acc[j].y = red8(acc[j].y);
        acc[j].z = red8(acc[j].z);
        acc[j].w = red8(acc[j].w);
    }
    if (r == 7) {                                     // lane 8q+7: window sum
        const float inv = 1.f / l_run;
        #pragma unroll
        for (int j = 0; j < 4; ++j)
            out4[j] = make_float4(acc[j].x * inv, acc[j].y * inv,
                                  acc[j].z * inv, acc[j].w * inv);
    }
}

extern "C" void kernel_launch(void* const* d_in, const int* in_sizes, int n_in,
                              void* d_out, int out_size, void* d_ws, size_t ws_size,
                              hipStream_t stream) {
    const float* h   = (const float*)d_in[0];   // (M, DH)
    const float* x   = (const float*)d_in[1];   // (N, DX)
    const float* a   = (const float*)d_in[2];   // (DH, DX)
    const int*   seg = (const int*)  d_in[3];   // (N,) sorted
    float* out = (float*)d_out;                 // (M, DX)

    int*   starts = (int*)d_ws;                             // (MSEG+1,)
    float* proj   = (float*)((char*)d_ws + 32768);          // (MSEG, DDIM)

    seg_starts_kernel<<<(NNODE + 255) / 256, 256, 0, stream>>>(seg, starts);
    proj_kernel<<<MSEG / PROJ_ROWS, 256, 0, stream>>>(h, a, proj);
    attn_seg_kernel<<<MSEG / WPB, 256, 0, stream>>>(x, proj, starts, out);
}